// Round 1
// baseline (751.722 us; speedup 1.0000x reference)
//
#include <hip/hip_runtime.h>
#include <hip/hip_bf16.h>
#include <type_traits>
#include <stdint.h>

typedef short bf16x8 __attribute__((ext_vector_type(8)));
typedef float f32x4 __attribute__((ext_vector_type(4)));

__device__ inline short f2bf(float f) {
    union { float f; uint32_t u; } v;
    v.f = f;
    uint32_t r = (v.u + 0x7FFFu + ((v.u >> 16) & 1u)) >> 16;
    return (short)(uint16_t)r;
}

__device__ inline bf16x8 cvt8(const float4& a, const float4& b) {
    bf16x8 o;
    o[0] = f2bf(a.x); o[1] = f2bf(a.y); o[2] = f2bf(a.z); o[3] = f2bf(a.w);
    o[4] = f2bf(b.x); o[5] = f2bf(b.y); o[6] = f2bf(b.z); o[7] = f2bf(b.w);
    return o;
}

// C[M,N] = A[M,K] @ W[K,N] + bias[N]
// TA in {float, short(bf16)}; W always float; TC in {short(bf16), float}
template <typename TA, typename TC>
__global__ __launch_bounds__(256) void gemm_bias(
    const TA* __restrict__ A, const float* __restrict__ W,
    const float* __restrict__ bias, TC* __restrict__ C,
    int M, int N, int K)
{
    constexpr int BM = 128, BN = 128, BK = 32;
    __shared__ short As[BM][BK + 8];   // [m][k]
    __shared__ short Bs[BN][BK + 8];   // [n][k]  (W transposed)

    const int t = threadIdx.x;
    const int m0 = blockIdx.x * BM;
    const int n0 = blockIdx.y * BN;
    const int w = t >> 6, lane = t & 63;
    const int wm = (w >> 1) * 64, wn = (w & 1) * 64;
    const int lr = lane & 15, lg = lane >> 4;

    f32x4 acc[4][4] = {};

    const int sar = t >> 1;          // A stage row 0..127
    const int sak = (t & 1) * 16;    // 0 or 16
    const int swk = t >> 3;          // W stage k-row 0..31
    const int swn = (t & 7) * 16;    // 0..112

    for (int kk = 0; kk < K; kk += BK) {
        __syncthreads();
        // ---- stage A tile [128][32] -> bf16 LDS ----
        if constexpr (std::is_same<TA, float>::value) {
            const float* ap = A + (size_t)(m0 + sar) * K + kk + sak;
            float4 a0 = ((const float4*)ap)[0];
            float4 a1 = ((const float4*)ap)[1];
            float4 a2 = ((const float4*)ap)[2];
            float4 a3 = ((const float4*)ap)[3];
            *(bf16x8*)&As[sar][sak]     = cvt8(a0, a1);
            *(bf16x8*)&As[sar][sak + 8] = cvt8(a2, a3);
        } else {
            const short* ap = (const short*)A + (size_t)(m0 + sar) * K + kk + sak;
            *(bf16x8*)&As[sar][sak]     = ((const bf16x8*)ap)[0];
            *(bf16x8*)&As[sar][sak + 8] = ((const bf16x8*)ap)[1];
        }
        // ---- stage W tile [32][128] transposed -> Bs[n][k] ----
        {
            const float* wp = W + (size_t)(kk + swk) * N + n0 + swn;
            float4 w0 = ((const float4*)wp)[0];
            float4 w1 = ((const float4*)wp)[1];
            float4 w2 = ((const float4*)wp)[2];
            float4 w3 = ((const float4*)wp)[3];
            Bs[swn +  0][swk] = f2bf(w0.x); Bs[swn +  1][swk] = f2bf(w0.y);
            Bs[swn +  2][swk] = f2bf(w0.z); Bs[swn +  3][swk] = f2bf(w0.w);
            Bs[swn +  4][swk] = f2bf(w1.x); Bs[swn +  5][swk] = f2bf(w1.y);
            Bs[swn +  6][swk] = f2bf(w1.z); Bs[swn +  7][swk] = f2bf(w1.w);
            Bs[swn +  8][swk] = f2bf(w2.x); Bs[swn +  9][swk] = f2bf(w2.y);
            Bs[swn + 10][swk] = f2bf(w2.z); Bs[swn + 11][swk] = f2bf(w2.w);
            Bs[swn + 12][swk] = f2bf(w3.x); Bs[swn + 13][swk] = f2bf(w3.y);
            Bs[swn + 14][swk] = f2bf(w3.z); Bs[swn + 15][swk] = f2bf(w3.w);
        }
        __syncthreads();

        bf16x8 af[4], bfr[4];
        #pragma unroll
        for (int i = 0; i < 4; ++i)
            af[i] = *(const bf16x8*)&As[wm + i * 16 + lr][lg * 8];
        #pragma unroll
        for (int j = 0; j < 4; ++j)
            bfr[j] = *(const bf16x8*)&Bs[wn + j * 16 + lr][lg * 8];
        #pragma unroll
        for (int i = 0; i < 4; ++i)
            #pragma unroll
            for (int j = 0; j < 4; ++j)
                acc[i][j] = __builtin_amdgcn_mfma_f32_16x16x32_bf16(af[i], bfr[j], acc[i][j], 0, 0, 0);
    }

    // epilogue: D layout col=lane&15, row=(lane>>4)*4+reg
    #pragma unroll
    for (int i = 0; i < 4; ++i) {
        #pragma unroll
        for (int j = 0; j < 4; ++j) {
            #pragma unroll
            for (int r = 0; r < 4; ++r) {
                int row = m0 + wm + i * 16 + lg * 4 + r;
                int col = n0 + wn + j * 16 + lr;
                float v = acc[i][j][r] + bias[col];
                if constexpr (std::is_same<TC, short>::value)
                    C[(size_t)row * N + col] = f2bf(v);
                else
                    C[(size_t)row * N + col] = v;
            }
        }
    }
}

// Flash attention: Qb [B*S, 16*128] bf16, Kb/Vb [B*S, 4*128] bf16 -> Ob [B*S, 16*128] bf16
// NO 1/sqrt(D) scaling (faithful to reference).
__global__ __launch_bounds__(256) void attn_kernel(
    const short* __restrict__ Qb, const short* __restrict__ Kb,
    const short* __restrict__ Vb, short* __restrict__ Ob)
{
    const int S = 2048;
    const int qt = blockIdx.x;       // 0..31 (q tile of 64)
    const int bh = blockIdx.y;       // 0..31
    const int b = bh >> 4, h = bh & 15, g = h >> 2;

    const int t = threadIdx.x, w = t >> 6, lane = t & 63;
    const int lr = lane & 15, lg = lane >> 4;

    __shared__ short Ks[32][136];    // [kv][d]
    __shared__ short Vt[128][40];    // [d][kv] (transposed)
    __shared__ short Pl[4][16][40];  // per-wave P [q][kv]

    const int q0 = qt * 64 + w * 16;

    // Q fragments in registers: A-frag row = lr, k = lg*8+j
    const short* qrow = Qb + ((size_t)(b * S + q0 + lr) * 2048) + h * 128;
    bf16x8 qf[4];
    #pragma unroll
    for (int kc = 0; kc < 4; ++kc)
        qf[kc] = *(const bf16x8*)(qrow + kc * 32 + lg * 8);

    f32x4 ao[8] = {};                // [d0][r]
    float m_r[4], l_r[4];
    #pragma unroll
    for (int r = 0; r < 4; ++r) { m_r[r] = -1e30f; l_r[r] = 0.0f; }

    const int sr = t >> 3;           // stage row 0..31
    const int sd = (t & 7) * 16;     // stage d 0..112

    for (int kv = 0; kv < S; kv += 32) {
        __syncthreads();
        // ---- stage K [32][128] and V transposed [128][32] ----
        {
            const short* kp = Kb + ((size_t)(b * S + kv + sr) * 512) + g * 128 + sd;
            *(bf16x8*)&Ks[sr][sd]     = ((const bf16x8*)kp)[0];
            *(bf16x8*)&Ks[sr][sd + 8] = ((const bf16x8*)kp)[1];
            const short* vp = Vb + ((size_t)(b * S + kv + sr) * 512) + g * 128 + sd;
            bf16x8 v0 = ((const bf16x8*)vp)[0];
            bf16x8 v1 = ((const bf16x8*)vp)[1];
            #pragma unroll
            for (int i = 0; i < 8; ++i) Vt[sd + i][sr] = v0[i];
            #pragma unroll
            for (int i = 0; i < 8; ++i) Vt[sd + 8 + i][sr] = v1[i];
        }
        __syncthreads();

        // ---- QK^T: scores [16 q][32 kv], 8 MFMA ----
        f32x4 sc[2] = {};
        #pragma unroll
        for (int kc = 0; kc < 4; ++kc) {
            #pragma unroll
            for (int f = 0; f < 2; ++f) {
                bf16x8 kb = *(const bf16x8*)&Ks[f * 16 + lr][kc * 32 + lg * 8];
                sc[f] = __builtin_amdgcn_mfma_f32_16x16x32_bf16(qf[kc], kb, sc[f], 0, 0, 0);
            }
        }

        // ---- online softmax (row q = lg*4+r, col kv = f*16+lr) ----
        float sc_scale[4];
        #pragma unroll
        for (int r = 0; r < 4; ++r) {
            float mx = fmaxf(sc[0][r], sc[1][r]);
            mx = fmaxf(mx, __shfl_xor(mx, 1));
            mx = fmaxf(mx, __shfl_xor(mx, 2));
            mx = fmaxf(mx, __shfl_xor(mx, 4));
            mx = fmaxf(mx, __shfl_xor(mx, 8));
            float mnew = fmaxf(m_r[r], mx);
            float scale = exp2f((m_r[r] - mnew) * 1.44269504089f);
            float p0 = exp2f((sc[0][r] - mnew) * 1.44269504089f);
            float p1 = exp2f((sc[1][r] - mnew) * 1.44269504089f);
            float rs = p0 + p1;
            rs += __shfl_xor(rs, 1);
            rs += __shfl_xor(rs, 2);
            rs += __shfl_xor(rs, 4);
            rs += __shfl_xor(rs, 8);
            l_r[r] = l_r[r] * scale + rs;
            m_r[r] = mnew;
            sc_scale[r] = scale;
            Pl[w][lg * 4 + r][lr]      = f2bf(p0);
            Pl[w][lg * 4 + r][16 + lr] = f2bf(p1);
        }
        #pragma unroll
        for (int d0 = 0; d0 < 8; ++d0)
            #pragma unroll
            for (int r = 0; r < 4; ++r)
                ao[d0][r] *= sc_scale[r];

        __syncthreads();   // make per-wave P writes visible (conservative)

        // ---- PV: O[16 q][128 d] += P[16][32] @ V[32][128], 8 MFMA ----
        bf16x8 pf = *(const bf16x8*)&Pl[w][lr][lg * 8];
        #pragma unroll
        for (int d0 = 0; d0 < 8; ++d0) {
            bf16x8 vf = *(const bf16x8*)&Vt[d0 * 16 + lr][lg * 8];
            ao[d0] = __builtin_amdgcn_mfma_f32_16x16x32_bf16(pf, vf, ao[d0], 0, 0, 0);
        }
    }

    // ---- epilogue: O /= l, store bf16 ----
    #pragma unroll
    for (int d0 = 0; d0 < 8; ++d0) {
        #pragma unroll
        for (int r = 0; r < 4; ++r) {
            float v = ao[d0][r] / l_r[r];
            int q = q0 + lg * 4 + r;
            Ob[(size_t)(b * S + q) * 2048 + h * 128 + d0 * 16 + lr] = f2bf(v);
        }
    }
}

extern "C" void kernel_launch(void* const* d_in, const int* in_sizes, int n_in,
                              void* d_out, int out_size, void* d_ws, size_t ws_size,
                              hipStream_t stream)
{
    const float* query = (const float*)d_in[0];
    const float* key   = (const float*)d_in[1];
    const float* value = (const float*)d_in[2];
    const float* Wq    = (const float*)d_in[3];
    const float* bq    = (const float*)d_in[4];
    const float* Wk    = (const float*)d_in[5];
    const float* bk    = (const float*)d_in[6];
    const float* Wv    = (const float*)d_in[7];
    const float* bv    = (const float*)d_in[8];
    const float* Wo    = (const float*)d_in[9];
    const float* bo    = (const float*)d_in[10];
    float* out = (float*)d_out;

    const int BS = 4096;  // B*S
    short* Qb = (short*)d_ws;                     // [4096, 2048]
    short* Kb = Qb + (size_t)BS * 2048;           // [4096, 512]
    short* Vb = Kb + (size_t)BS * 512;            // [4096, 512]
    short* Ob = Vb + (size_t)BS * 512;            // [4096, 2048]

    dim3 blk(256);
    // Q = query @ Wq + bq
    gemm_bias<float, short><<<dim3(BS / 128, 2048 / 128), blk, 0, stream>>>(
        query, Wq, bq, Qb, BS, 2048, 2048);
    // K = key @ Wk + bk
    gemm_bias<float, short><<<dim3(BS / 128, 512 / 128), blk, 0, stream>>>(
        key, Wk, bk, Kb, BS, 512, 2048);
    // V = value @ Wv + bv
    gemm_bias<float, short><<<dim3(BS / 128, 512 / 128), blk, 0, stream>>>(
        value, Wv, bv, Vb, BS, 512, 2048);
    // attention
    attn_kernel<<<dim3(2048 / 64, 32), blk, 0, stream>>>(Qb, Kb, Vb, Ob);
    // out = O @ Wo + bo
    gemm_bias<short, float><<<dim3(BS / 128, 2048 / 128), blk, 0, stream>>>(
        Ob, Wo, bo, out, BS, 2048, 2048);
}

// Round 2
// 364.287 us; speedup vs baseline: 2.0635x; 2.0635x over previous
//
#include <hip/hip_runtime.h>
#include <hip/hip_bf16.h>
#include <type_traits>
#include <stdint.h>

typedef short bf16x8 __attribute__((ext_vector_type(8)));
typedef float f32x4 __attribute__((ext_vector_type(4)));

#define GLL16(gp, lp) __builtin_amdgcn_global_load_lds( \
    (const __attribute__((address_space(1))) void*)(gp), \
    (__attribute__((address_space(3))) void*)(lp), 16, 0, 0)

__device__ inline short f2bf(float f) {
    union { float f; uint32_t u; } v;
    v.f = f;
    uint32_t r = (v.u + 0x7FFFu + ((v.u >> 16) & 1u)) >> 16;
    return (short)(uint16_t)r;
}

__device__ inline bf16x8 cvt8(const float4& a, const float4& b) {
    bf16x8 o;
    o[0] = f2bf(a.x); o[1] = f2bf(a.y); o[2] = f2bf(a.z); o[3] = f2bf(a.w);
    o[4] = f2bf(b.x); o[5] = f2bf(b.y); o[6] = f2bf(b.z); o[7] = f2bf(b.w);
    return o;
}

// ---------------- elementwise f32 -> bf16 convert ----------------
__global__ __launch_bounds__(256) void cvtk(const float* __restrict__ in,
                                            short* __restrict__ out, int n8)
{
    int i = blockIdx.x * blockDim.x + threadIdx.x;
    int stride = gridDim.x * blockDim.x;
    for (; i < n8; i += stride) {
        const float4* p = (const float4*)(in + (size_t)i * 8);
        float4 a = p[0], b = p[1];
        *(bf16x8*)(out + (size_t)i * 8) = cvt8(a, b);
    }
}

// ---------------- W [K][N] f32 -> WT [N][K] bf16 ----------------
__global__ __launch_bounds__(256) void transW(const float* __restrict__ W,
                                              short* __restrict__ WT, int K, int N)
{
    __shared__ short T[64][65];   // T[n][k]
    int n0 = blockIdx.x * 64, k0 = blockIdx.y * 64;
    int t = threadIdx.x;
    int kl = t >> 2, nb = (t & 3) * 16;
    const float* wp = W + (size_t)(k0 + kl) * N + n0 + nb;
    #pragma unroll
    for (int j = 0; j < 16; ++j) T[nb + j][kl] = f2bf(wp[j]);
    __syncthreads();
    int nl = t >> 2, kb = (t & 3) * 16;
    short* op = WT + (size_t)(n0 + nl) * K + k0 + kb;
    #pragma unroll
    for (int j = 0; j < 16; ++j) op[j] = T[nl][kb + j];
}

// ---------------- Vb [B*S][512] bf16 -> Vt [8][128][2048] bf16 ----------------
__global__ __launch_bounds__(256) void transV(const short* __restrict__ Vb,
                                              short* __restrict__ Vt)
{
    __shared__ short T[64][65];   // T[d][s]
    int s0 = blockIdx.x * 64, d0 = blockIdx.y * 64, bg = blockIdx.z;
    int b = bg >> 2, g = bg & 3;
    int t = threadIdx.x;
    int sl = t >> 2, db = (t & 3) * 16;
    const short* vp = Vb + (size_t)(b * 2048 + s0 + sl) * 512 + g * 128 + d0 + db;
    #pragma unroll
    for (int j = 0; j < 16; ++j) T[db + j][sl] = vp[j];
    __syncthreads();
    int dl = t >> 2, sb = (t & 3) * 16;
    short* op = Vt + (size_t)(bg * 128 + d0 + dl) * 2048 + s0 + sb;
    #pragma unroll
    for (int j = 0; j < 16; ++j) op[j] = T[dl][sb + j];
}

// ---------------- bf16 GEMM, B pre-transposed: C = A[M,K] @ BT[N,K]^T + bias ----------------
// m97 structure: global_load_lds w=16, BK=64, XOR-swizzled LDS (source-permuted).
template <typename TC>
__global__ __launch_bounds__(256) void gemm_bt(
    const short* __restrict__ A, const short* __restrict__ BT,
    const float* __restrict__ bias, TC* __restrict__ C,
    int M, int N, int K)
{
    __shared__ short As[128 * 64];
    __shared__ short Bs[128 * 64];
    const int t = threadIdx.x, w = t >> 6, lane = t & 63;
    const int lr = lane & 15, lg = lane >> 4;
    const int m0 = blockIdx.x * 128, n0 = blockIdx.y * 128;
    const int wm = (w >> 1) * 64, wn = (w & 1) * 64;
    f32x4 acc[4][4] = {};

    const int lrow = lane >> 3;                    // 0..7
    const int lcg = (lane & 7) ^ (lrow & 7);       // swizzled source chunk
    const int sw = lr & 7;                         // read-side swizzle

    for (int kk = 0; kk < K; kk += 64) {
        __syncthreads();
        #pragma unroll
        for (int i = 0; i < 4; ++i) {
            int row = w * 32 + i * 8 + lrow;
            GLL16(A  + (size_t)(m0 + row) * K + kk + lcg * 8, &As[(w * 32 + i * 8) * 64]);
            GLL16(BT + (size_t)(n0 + row) * K + kk + lcg * 8, &Bs[(w * 32 + i * 8) * 64]);
        }
        __syncthreads();
        #pragma unroll
        for (int kc = 0; kc < 2; ++kc) {
            bf16x8 af[4], bfr[4];
            #pragma unroll
            for (int i = 0; i < 4; ++i)
                af[i] = *(const bf16x8*)&As[(wm + i * 16 + lr) * 64 + (((kc * 4 + lg) ^ sw) * 8)];
            #pragma unroll
            for (int j = 0; j < 4; ++j)
                bfr[j] = *(const bf16x8*)&Bs[(wn + j * 16 + lr) * 64 + (((kc * 4 + lg) ^ sw) * 8)];
            #pragma unroll
            for (int i = 0; i < 4; ++i)
                #pragma unroll
                for (int j = 0; j < 4; ++j)
                    acc[i][j] = __builtin_amdgcn_mfma_f32_16x16x32_bf16(af[i], bfr[j], acc[i][j], 0, 0, 0);
        }
    }

    #pragma unroll
    for (int i = 0; i < 4; ++i) {
        #pragma unroll
        for (int j = 0; j < 4; ++j) {
            #pragma unroll
            for (int r = 0; r < 4; ++r) {
                int row = m0 + wm + i * 16 + lg * 4 + r;
                int col = n0 + wn + j * 16 + lr;
                float v = acc[i][j][r] + bias[col];
                if constexpr (std::is_same<TC, short>::value)
                    C[(size_t)row * N + col] = f2bf(v);
                else
                    C[(size_t)row * N + col] = v;
            }
        }
    }
}

// ---------------- round-1 fused-convert GEMM (fallback path) ----------------
template <typename TA, typename TC>
__global__ __launch_bounds__(256) void gemm_bias(
    const TA* __restrict__ A, const float* __restrict__ W,
    const float* __restrict__ bias, TC* __restrict__ C,
    int M, int N, int K)
{
    constexpr int BM = 128, BN = 128, BK = 32;
    __shared__ short As[BM][BK + 8];
    __shared__ short Bs[BN][BK + 8];

    const int t = threadIdx.x;
    const int m0 = blockIdx.x * BM;
    const int n0 = blockIdx.y * BN;
    const int w = t >> 6, lane = t & 63;
    const int wm = (w >> 1) * 64, wn = (w & 1) * 64;
    const int lr = lane & 15, lg = lane >> 4;

    f32x4 acc[4][4] = {};

    const int sar = t >> 1;
    const int sak = (t & 1) * 16;
    const int swk = t >> 3;
    const int swn = (t & 7) * 16;

    for (int kk = 0; kk < K; kk += BK) {
        __syncthreads();
        if constexpr (std::is_same<TA, float>::value) {
            const float* ap = A + (size_t)(m0 + sar) * K + kk + sak;
            float4 a0 = ((const float4*)ap)[0];
            float4 a1 = ((const float4*)ap)[1];
            float4 a2 = ((const float4*)ap)[2];
            float4 a3 = ((const float4*)ap)[3];
            *(bf16x8*)&As[sar][sak]     = cvt8(a0, a1);
            *(bf16x8*)&As[sar][sak + 8] = cvt8(a2, a3);
        } else {
            const short* ap = (const short*)A + (size_t)(m0 + sar) * K + kk + sak;
            *(bf16x8*)&As[sar][sak]     = ((const bf16x8*)ap)[0];
            *(bf16x8*)&As[sar][sak + 8] = ((const bf16x8*)ap)[1];
        }
        {
            const float* wp = W + (size_t)(kk + swk) * N + n0 + swn;
            float4 w0 = ((const float4*)wp)[0];
            float4 w1 = ((const float4*)wp)[1];
            float4 w2 = ((const float4*)wp)[2];
            float4 w3 = ((const float4*)wp)[3];
            Bs[swn +  0][swk] = f2bf(w0.x); Bs[swn +  1][swk] = f2bf(w0.y);
            Bs[swn +  2][swk] = f2bf(w0.z); Bs[swn +  3][swk] = f2bf(w0.w);
            Bs[swn +  4][swk] = f2bf(w1.x); Bs[swn +  5][swk] = f2bf(w1.y);
            Bs[swn +  6][swk] = f2bf(w1.z); Bs[swn +  7][swk] = f2bf(w1.w);
            Bs[swn +  8][swk] = f2bf(w2.x); Bs[swn +  9][swk] = f2bf(w2.y);
            Bs[swn + 10][swk] = f2bf(w2.z); Bs[swn + 11][swk] = f2bf(w2.w);
            Bs[swn + 12][swk] = f2bf(w3.x); Bs[swn + 13][swk] = f2bf(w3.y);
            Bs[swn + 14][swk] = f2bf(w3.z); Bs[swn + 15][swk] = f2bf(w3.w);
        }
        __syncthreads();

        bf16x8 af[4], bfr[4];
        #pragma unroll
        for (int i = 0; i < 4; ++i)
            af[i] = *(const bf16x8*)&As[wm + i * 16 + lr][lg * 8];
        #pragma unroll
        for (int j = 0; j < 4; ++j)
            bfr[j] = *(const bf16x8*)&Bs[wn + j * 16 + lr][lg * 8];
        #pragma unroll
        for (int i = 0; i < 4; ++i)
            #pragma unroll
            for (int j = 0; j < 4; ++j)
                acc[i][j] = __builtin_amdgcn_mfma_f32_16x16x32_bf16(af[i], bfr[j], acc[i][j], 0, 0, 0);
    }

    #pragma unroll
    for (int i = 0; i < 4; ++i) {
        #pragma unroll
        for (int j = 0; j < 4; ++j) {
            #pragma unroll
            for (int r = 0; r < 4; ++r) {
                int row = m0 + wm + i * 16 + lg * 4 + r;
                int col = n0 + wn + j * 16 + lr;
                float v = acc[i][j][r] + bias[col];
                if constexpr (std::is_same<TC, short>::value)
                    C[(size_t)row * N + col] = f2bf(v);
                else
                    C[(size_t)row * N + col] = v;
            }
        }
    }
}

// ---------------- flash attention: KVBLK=64, swizzled LDS, gll staging ----------------
// Qb [B*S,2048] bf16, Kb [B*S,512] bf16, Vt [8][128][2048] bf16 -> Ob [B*S,2048] bf16
__global__ __launch_bounds__(256, 4) void attn_kernel(
    const short* __restrict__ Qb, const short* __restrict__ Kb,
    const short* __restrict__ Vt, short* __restrict__ Ob)
{
    const int S = 2048;
    __shared__ short Ks[64 * 128];    // 16 KB, swizzled chunks
    __shared__ short Vs[128 * 64];    // 16 KB, swizzled chunks
    __shared__ short Pl[4][16 * 64];  // 8 KB per-wave P, swizzled

    const int qt = blockIdx.x, bh = blockIdx.y;
    const int b = bh >> 4, h = bh & 15, g = h >> 2, bg = b * 4 + g;
    const int t = threadIdx.x, w = t >> 6, lane = t & 63;
    const int lr = lane & 15, lg = lane >> 4;
    const int q0 = qt * 64 + w * 16;

    // Q fragments hoisted to registers
    const short* qrow = Qb + ((size_t)(b * S + q0 + lr) * 2048) + h * 128;
    bf16x8 qf[4];
    #pragma unroll
    for (int kc = 0; kc < 4; ++kc)
        qf[kc] = *(const bf16x8*)(qrow + kc * 32 + lg * 8);

    f32x4 ao[8] = {};
    float m_r[4], l_r[4];
    #pragma unroll
    for (int r = 0; r < 4; ++r) { m_r[r] = -1e30f; l_r[r] = 0.0f; }

    const int Lr4 = lane >> 4, Lc4 = lane & 15;  // K staging (4 rows/KB)
    const int Lr3 = lane >> 3, Lc3 = lane & 7;   // V staging (8 rows/KB)
    const int swp = lr & 7;

    for (int kv0 = 0; kv0 < S; kv0 += 64) {
        __syncthreads();
        // stage K [64][128]: wave w rows w*16 .. w*16+15
        #pragma unroll
        for (int i = 0; i < 4; ++i) {
            int r = w * 16 + i * 4 + Lr4;
            int cg = Lc4 ^ (r & 7);
            GLL16(Kb + (size_t)(b * S + kv0 + r) * 512 + g * 128 + cg * 8,
                  &Ks[(w * 16 + i * 4) * 128]);
        }
        // stage V^T [128][64]: wave w rows w*32 .. w*32+31
        #pragma unroll
        for (int i = 0; i < 4; ++i) {
            int r = w * 32 + i * 8 + Lr3;
            int cg = Lc3 ^ (r & 7);
            GLL16(Vt + (size_t)(bg * 128 + r) * 2048 + kv0 + cg * 8,
                  &Vs[(w * 32 + i * 8) * 64]);
        }
        __syncthreads();

        // QK^T -> scores [16 q][64 kv]
        f32x4 sc[4] = {};
        #pragma unroll
        for (int kc = 0; kc < 4; ++kc) {
            #pragma unroll
            for (int f = 0; f < 4; ++f) {
                int row = f * 16 + lr;
                bf16x8 kb = *(const bf16x8*)&Ks[row * 128 + (((kc * 4 + lg) ^ (row & 7)) * 8)];
                sc[f] = __builtin_amdgcn_mfma_f32_16x16x32_bf16(qf[kc], kb, sc[f], 0, 0, 0);
            }
        }

        // online softmax; rows q = lg*4+r, cols kv = f*16+lr
        float scale_r[4];
        #pragma unroll
        for (int r = 0; r < 4; ++r) {
            float mx = fmaxf(fmaxf(sc[0][r], sc[1][r]), fmaxf(sc[2][r], sc[3][r]));
            mx = fmaxf(mx, __shfl_xor(mx, 1));
            mx = fmaxf(mx, __shfl_xor(mx, 2));
            mx = fmaxf(mx, __shfl_xor(mx, 4));
            mx = fmaxf(mx, __shfl_xor(mx, 8));
            float mnew = fmaxf(m_r[r], mx);
            float sc8 = exp2f((m_r[r] - mnew) * 1.44269504089f);
            float p0 = exp2f((sc[0][r] - mnew) * 1.44269504089f);
            float p1 = exp2f((sc[1][r] - mnew) * 1.44269504089f);
            float p2 = exp2f((sc[2][r] - mnew) * 1.44269504089f);
            float p3 = exp2f((sc[3][r] - mnew) * 1.44269504089f);
            float rs = (p0 + p1) + (p2 + p3);
            rs += __shfl_xor(rs, 1);
            rs += __shfl_xor(rs, 2);
            rs += __shfl_xor(rs, 4);
            rs += __shfl_xor(rs, 8);
            l_r[r] = l_r[r] * sc8 + rs;
            m_r[r] = mnew;
            scale_r[r] = sc8;
            int q = lg * 4 + r;
            int cw0 = (lr >> 3);
            Pl[w][q * 64 + (((0 + cw0) ^ (q & 7)) * 8) + (lr & 7)] = f2bf(p0);
            Pl[w][q * 64 + (((2 + cw0) ^ (q & 7)) * 8) + (lr & 7)] = f2bf(p1);
            Pl[w][q * 64 + (((4 + cw0) ^ (q & 7)) * 8) + (lr & 7)] = f2bf(p2);
            Pl[w][q * 64 + (((6 + cw0) ^ (q & 7)) * 8) + (lr & 7)] = f2bf(p3);
        }
        #pragma unroll
        for (int d0 = 0; d0 < 8; ++d0)
            #pragma unroll
            for (int r = 0; r < 4; ++r)
                ao[d0][r] *= scale_r[r];

        // PV (same-wave LDS RAW: compiler inserts lgkmcnt; no block barrier needed)
        bf16x8 pf0 = *(const bf16x8*)&Pl[w][lr * 64 + (((0 + lg) ^ swp) * 8)];
        bf16x8 pf1 = *(const bf16x8*)&Pl[w][lr * 64 + (((4 + lg) ^ swp) * 8)];
        #pragma unroll
        for (int d0 = 0; d0 < 8; ++d0) {
            int row = d0 * 16 + lr;
            bf16x8 v0 = *(const bf16x8*)&Vs[row * 64 + (((0 + lg) ^ (row & 7)) * 8)];
            bf16x8 v1 = *(const bf16x8*)&Vs[row * 64 + (((4 + lg) ^ (row & 7)) * 8)];
            ao[d0] = __builtin_amdgcn_mfma_f32_16x16x32_bf16(pf0, v0, ao[d0], 0, 0, 0);
            ao[d0] = __builtin_amdgcn_mfma_f32_16x16x32_bf16(pf1, v1, ao[d0], 0, 0, 0);
        }
    }

    #pragma unroll
    for (int d0 = 0; d0 < 8; ++d0) {
        #pragma unroll
        for (int r = 0; r < 4; ++r) {
            float v = ao[d0][r] / l_r[r];
            int q = q0 + lg * 4 + r;
            Ob[(size_t)(b * S + q) * 2048 + h * 128 + d0 * 16 + lr] = f2bf(v);
        }
    }
}

extern "C" void kernel_launch(void* const* d_in, const int* in_sizes, int n_in,
                              void* d_out, int out_size, void* d_ws, size_t ws_size,
                              hipStream_t stream)
{
    const float* query = (const float*)d_in[0];
    const float* key   = (const float*)d_in[1];
    const float* value = (const float*)d_in[2];
    const float* Wq    = (const float*)d_in[3];
    const float* bq    = (const float*)d_in[4];
    const float* Wk    = (const float*)d_in[5];
    const float* bk    = (const float*)d_in[6];
    const float* Wv    = (const float*)d_in[7];
    const float* bv    = (const float*)d_in[8];
    const float* Wo    = (const float*)d_in[9];
    const float* bo    = (const float*)d_in[10];
    float* out = (float*)d_out;

    const int BS = 4096;
    char* ws = (char*)d_ws;
    dim3 blk(256);

    if (ws_size >= (size_t)67108864) {
        // ---- full path: all-bf16 GEMMs via pre-convert/pre-transpose ----
        short* Qb  = (short*)(ws + 0);          // 16 MB [4096,2048]
        short* Kb  = (short*)(ws + 16777216);   //  4 MB [4096,512]
        short* Vb  = (short*)(ws + 20971520);   //  4 MB [4096,512]
        short* Vtg = (short*)(ws + 25165824);   //  4 MB [8,128,2048]
        short* WqT = (short*)(ws + 29360128);   //  8 MB [2048,2048]
        short* WkT = (short*)(ws + 37748736);   //  2 MB [512,2048]
        short* WvT = (short*)(ws + 39845888);   //  2 MB [512,2048]
        short* WoT = (short*)(ws + 41943040);   //  8 MB [2048,2048]
        short* Xbf = (short*)(ws + 50331648);   // 16 MB shared: q/k/v bf16, then Ob

        transW<<<dim3(32, 32), blk, 0, stream>>>(Wq, WqT, 2048, 2048);
        transW<<<dim3(8, 32),  blk, 0, stream>>>(Wk, WkT, 2048, 512);
        transW<<<dim3(8, 32),  blk, 0, stream>>>(Wv, WvT, 2048, 512);
        transW<<<dim3(32, 32), blk, 0, stream>>>(Wo, WoT, 2048, 2048);

        cvtk<<<2048, blk, 0, stream>>>(query, Xbf, BS * 2048 / 8);
        gemm_bt<short><<<dim3(32, 16), blk, 0, stream>>>(Xbf, WqT, bq, Qb, BS, 2048, 2048);
        cvtk<<<2048, blk, 0, stream>>>(key, Xbf, BS * 2048 / 8);
        gemm_bt<short><<<dim3(32, 4), blk, 0, stream>>>(Xbf, WkT, bk, Kb, BS, 512, 2048);
        cvtk<<<2048, blk, 0, stream>>>(value, Xbf, BS * 2048 / 8);
        gemm_bt<short><<<dim3(32, 4), blk, 0, stream>>>(Xbf, WvT, bv, Vb, BS, 512, 2048);

        transV<<<dim3(32, 2, 8), blk, 0, stream>>>(Vb, Vtg);
        attn_kernel<<<dim3(32, 32), blk, 0, stream>>>(Qb, Kb, Vtg, Xbf /*Ob*/);
        gemm_bt<float><<<dim3(32, 16), blk, 0, stream>>>(Xbf, WoT, bo, out, BS, 2048, 2048);
    } else {
        // ---- fallback: round-1 fused GEMMs + new attention ----
        short* Qb  = (short*)(ws + 0);
        short* Kb  = (short*)(ws + 16777216);
        short* Vb  = (short*)(ws + 20971520);
        short* Ob  = (short*)(ws + 25165824);
        short* Vtg = (short*)(ws + 41943040);

        gemm_bias<float, short><<<dim3(32, 16), blk, 0, stream>>>(query, Wq, bq, Qb, BS, 2048, 2048);
        gemm_bias<float, short><<<dim3(32, 4),  blk, 0, stream>>>(key, Wk, bk, Kb, BS, 512, 2048);
        gemm_bias<float, short><<<dim3(32, 4),  blk, 0, stream>>>(value, Wv, bv, Vb, BS, 512, 2048);
        transV<<<dim3(32, 2, 8), blk, 0, stream>>>(Vb, Vtg);
        attn_kernel<<<dim3(32, 32), blk, 0, stream>>>(Qb, Kb, Vtg, Ob);
        gemm_bias<short, float><<<dim3(32, 16), blk, 0, stream>>>(Ob, Wo, bo, out, BS, 2048, 2048);
    }
}

// Round 3
// 313.778 us; speedup vs baseline: 2.3957x; 1.1610x over previous
//
#include <hip/hip_runtime.h>
#include <hip/hip_bf16.h>
#include <type_traits>
#include <stdint.h>

typedef short bf16x8 __attribute__((ext_vector_type(8)));
typedef float f32x4 __attribute__((ext_vector_type(4)));

#define GLL16(gp, lp) __builtin_amdgcn_global_load_lds( \
    (const __attribute__((address_space(1))) void*)(gp), \
    (__attribute__((address_space(3))) void*)(lp), 16, 0, 0)

__device__ inline short f2bf(float f) {
    union { float f; uint32_t u; } v;
    v.f = f;
    uint32_t r = (v.u + 0x7FFFu + ((v.u >> 16) & 1u)) >> 16;
    return (short)(uint16_t)r;
}

__device__ inline bf16x8 cvt8(const float4& a, const float4& b) {
    bf16x8 o;
    o[0] = f2bf(a.x); o[1] = f2bf(a.y); o[2] = f2bf(a.z); o[3] = f2bf(a.w);
    o[4] = f2bf(b.x); o[5] = f2bf(b.y); o[6] = f2bf(b.z); o[7] = f2bf(b.w);
    return o;
}

// ---------------- single f32 -> bf16 convert (fallback path) ----------------
__global__ __launch_bounds__(256) void cvtk(const float* __restrict__ in,
                                            short* __restrict__ out, int n8)
{
    int i = blockIdx.x * blockDim.x + threadIdx.x;
    int stride = gridDim.x * blockDim.x;
    for (; i < n8; i += stride) {
        const float4* p = (const float4*)(in + (size_t)i * 8);
        float4 a = p[0], b = p[1];
        *(bf16x8*)(out + (size_t)i * 8) = cvt8(a, b);
    }
}

// ---------------- batched q,k,v f32 -> bf16 convert (full path) ----------------
__global__ __launch_bounds__(256) void cvt3(
    const float* __restrict__ q, const float* __restrict__ k, const float* __restrict__ v,
    short* __restrict__ Xq, short* __restrict__ Xk, short* __restrict__ Xv)
{
    const float* in; short* out;
    if (blockIdx.y == 0) { in = q; out = Xq; }
    else if (blockIdx.y == 1) { in = k; out = Xk; }
    else { in = v; out = Xv; }
    size_t i = (size_t)blockIdx.x * 256 + threadIdx.x;   // unit of 8 elems
    const float4* p = (const float4*)(in + i * 8);
    float4 a = p[0], b = p[1];
    *(bf16x8*)(out + i * 8) = cvt8(a, b);
}

// ---------------- batched W [K][N] f32 -> WT [N][K] bf16 (4 weights) ----------------
__global__ __launch_bounds__(256) void transW4(
    const float* __restrict__ W0, const float* __restrict__ W1,
    const float* __restrict__ W2, const float* __restrict__ W3,
    short* __restrict__ T0, short* __restrict__ T1,
    short* __restrict__ T2, short* __restrict__ T3)
{
    const int K = 2048;
    const float* W; short* T; int N;
    int z = blockIdx.z;
    if (z == 0)      { W = W0; T = T0; N = 2048; }
    else if (z == 1) { W = W1; T = T1; N = 512; }
    else if (z == 2) { W = W2; T = T2; N = 512; }
    else             { W = W3; T = T3; N = 2048; }
    int n0 = blockIdx.x * 64, k0 = blockIdx.y * 64;
    if (n0 >= N) return;
    __shared__ short Tt[64][65];
    int t = threadIdx.x;
    int kl = t >> 2, nb = (t & 3) * 16;
    const float* wp = W + (size_t)(k0 + kl) * N + n0 + nb;
    #pragma unroll
    for (int j = 0; j < 16; ++j) Tt[nb + j][kl] = f2bf(wp[j]);
    __syncthreads();
    int nl = t >> 2, kb = (t & 3) * 16;
    short* op = T + (size_t)(n0 + nl) * K + k0 + kb;
    #pragma unroll
    for (int j = 0; j < 16; ++j) op[j] = Tt[nl][kb + j];
}

// ---------------- Vb [B*S][512] bf16 -> Vt [8][128][2048] bf16 ----------------
__global__ __launch_bounds__(256) void transV(const short* __restrict__ Vb,
                                              short* __restrict__ Vt)
{
    __shared__ short T[64][65];
    int s0 = blockIdx.x * 64, d0 = blockIdx.y * 64, bg = blockIdx.z;
    int b = bg >> 2, g = bg & 3;
    int t = threadIdx.x;
    int sl = t >> 2, db = (t & 3) * 16;
    const short* vp = Vb + (size_t)(b * 2048 + s0 + sl) * 512 + g * 128 + d0 + db;
    #pragma unroll
    for (int j = 0; j < 16; ++j) T[db + j][sl] = vp[j];
    __syncthreads();
    int dl = t >> 2, sb = (t & 3) * 16;
    short* op = Vt + (size_t)(bg * 128 + d0 + dl) * 2048 + s0 + sb;
    #pragma unroll
    for (int j = 0; j < 16; ++j) op[j] = T[dl][sb + j];
}

// ---------------- bf16 GEMM core: C[M=4096,N] = A[.,K] @ BT[N,K]^T + bias ----------------
template <typename TC>
__device__ __forceinline__ void gemm_core(
    const short* __restrict__ A, const short* __restrict__ BT,
    const float* __restrict__ bias, TC* __restrict__ C,
    int N, int K, int m0, int n0, short* As, short* Bs)
{
    const int t = threadIdx.x, w = t >> 6, lane = t & 63;
    const int lr = lane & 15, lg = lane >> 4;
    const int wm = (w >> 1) * 64, wn = (w & 1) * 64;
    f32x4 acc[4][4] = {};

    const int lrow = lane >> 3;                 // 0..7
    const int lcg = (lane & 7) ^ (lrow & 7);    // pre-swizzled source chunk
    const int sw = lr & 7;

    // hoisted LDS read bases (loop-invariant)
    const short* abase[2]; const short* bbase[2];
    #pragma unroll
    for (int kc = 0; kc < 2; ++kc) {
        abase[kc] = &As[(wm + lr) * 64 + (((kc * 4 + lg) ^ sw) * 8)];
        bbase[kc] = &Bs[(wn + lr) * 64 + (((kc * 4 + lg) ^ sw) * 8)];
    }
    // loop-carried global source pointers
    const short* asrc = A  + (size_t)(m0 + w * 32 + lrow) * K + lcg * 8;
    const short* bsrc = BT + (size_t)(n0 + w * 32 + lrow) * K + lcg * 8;
    short* adst = &As[(w * 32) * 64];
    short* bdst = &Bs[(w * 32) * 64];

    for (int kk = 0; kk < K; kk += 64) {
        __syncthreads();
        #pragma unroll
        for (int i = 0; i < 4; ++i) {
            GLL16(asrc + (size_t)i * 8 * K, adst + i * 512);
            GLL16(bsrc + (size_t)i * 8 * K, bdst + i * 512);
        }
        asrc += 64; bsrc += 64;
        __syncthreads();
        #pragma unroll
        for (int kc = 0; kc < 2; ++kc) {
            bf16x8 af[4], bfr[4];
            #pragma unroll
            for (int i = 0; i < 4; ++i) af[i] = *(const bf16x8*)(abase[kc] + i * 1024);
            #pragma unroll
            for (int j = 0; j < 4; ++j) bfr[j] = *(const bf16x8*)(bbase[kc] + j * 1024);
            #pragma unroll
            for (int i = 0; i < 4; ++i)
                #pragma unroll
                for (int j = 0; j < 4; ++j)
                    acc[i][j] = __builtin_amdgcn_mfma_f32_16x16x32_bf16(af[i], bfr[j], acc[i][j], 0, 0, 0);
        }
    }

    #pragma unroll
    for (int i = 0; i < 4; ++i) {
        #pragma unroll
        for (int j = 0; j < 4; ++j) {
            #pragma unroll
            for (int r = 0; r < 4; ++r) {
                int row = m0 + wm + i * 16 + lg * 4 + r;
                int col = n0 + wn + j * 16 + lr;
                float v = acc[i][j][r] + bias[col];
                if constexpr (std::is_same<TC, short>::value)
                    C[(size_t)row * N + col] = f2bf(v);
                else
                    C[(size_t)row * N + col] = v;
            }
        }
    }
}

// standalone GEMM (grid = 32 * N/128, XCD-swizzled)
template <typename TC>
__global__ __launch_bounds__(256) void gemm_std(
    const short* __restrict__ A, const short* __restrict__ BT,
    const float* __restrict__ bias, TC* __restrict__ C, int N, int K)
{
    __shared__ short As[128 * 64];
    __shared__ short Bs[128 * 64];
    int bid = blockIdx.x;
    int chunk = gridDim.x >> 3;
    int wg = (bid & 7) * chunk + (bid >> 3);
    int m0 = (wg & 31) * 128, n0 = (wg >> 5) * 128;
    gemm_core<TC>(A, BT, bias, C, N, K, m0, n0, As, Bs);
}

// fused Q/K/V projection (768 blocks, XCD-swizzled)
__global__ __launch_bounds__(256) void gemm_qkv(
    const short* __restrict__ Xq, const short* __restrict__ Xk, const short* __restrict__ Xv,
    const short* __restrict__ WqT, const short* __restrict__ WkT, const short* __restrict__ WvT,
    const float* __restrict__ bq, const float* __restrict__ bk, const float* __restrict__ bv,
    short* __restrict__ Qb, short* __restrict__ Kb, short* __restrict__ Vb)
{
    __shared__ short As[128 * 64];
    __shared__ short Bs[128 * 64];
    int bid = blockIdx.x;
    int wg = (bid & 7) * 96 + (bid >> 3);      // 768/8 = 96 per XCD
    const short* A; const short* BT; const float* bi; short* C; int N; int l;
    if (wg < 512)      { l = wg;      A = Xq; BT = WqT; bi = bq; C = Qb; N = 2048; }
    else if (wg < 640) { l = wg - 512; A = Xk; BT = WkT; bi = bk; C = Kb; N = 512; }
    else               { l = wg - 640; A = Xv; BT = WvT; bi = bv; C = Vb; N = 512; }
    int m0 = (l & 31) * 128, n0 = (l >> 5) * 128;
    gemm_core<short>(A, BT, bi, C, N, 2048, m0, n0, As, Bs);
}

// ---------------- flash attention v3: hoisted addresses, subtile P, exact defer-rescale ----
__global__ __launch_bounds__(256, 4) void attn_kernel(
    const short* __restrict__ Qb, const short* __restrict__ Kb,
    const short* __restrict__ Vt, short* __restrict__ Ob)
{
    const int S = 2048;
    __shared__ short Ks[64 * 128];     // 16 KB
    __shared__ short Vs[128 * 64];     // 16 KB
    __shared__ short Pl[4][8 * 128];   // 8 KB; subtile: (kv>>3)*128 + q*8 + (kv&7)

    const int qt = blockIdx.x, bh = blockIdx.y;
    const int b = bh >> 4, h = bh & 15, g = h >> 2, bg = b * 4 + g;
    const int t = threadIdx.x, w = t >> 6, lane = t & 63;
    const int lr = lane & 15, lg = lane >> 4;
    const int q0 = qt * 64 + w * 16;
    const float C = 1.44269504089f;

    // Q fragments in registers
    const short* qrow = Qb + ((size_t)(b * S + q0 + lr) * 2048) + h * 128;
    bf16x8 qf[4];
    #pragma unroll
    for (int kc = 0; kc < 4; ++kc)
        qf[kc] = *(const bf16x8*)(qrow + kc * 32 + lg * 8);

    f32x4 ao[8] = {};
    float m_r[4], l_r[4];
    #pragma unroll
    for (int r = 0; r < 4; ++r) { m_r[r] = -1e30f; l_r[r] = 0.0f; }

    // ---- hoisted LDS read bases (all loop-invariant) ----
    const int sw = lr & 7;
    const short* kbase[4];
    #pragma unroll
    for (int kc = 0; kc < 4; ++kc)
        kbase[kc] = &Ks[lr * 128 + (((kc * 4 + lg) ^ sw) * 8)];
    const short* vbase[2];
    #pragma unroll
    for (int kc = 0; kc < 2; ++kc)
        vbase[kc] = &Vs[lr * 64 + (((kc * 4 + lg) ^ sw) * 8)];
    short* Pw = &Pl[w][0];
    short* pwb = Pw + ((lr >> 3) * 128 + lg * 32 + (lr & 7));  // + f*256 + r*8
    const short* prb = Pw + (lg * 128 + lr * 8);               // + kc*512

    // ---- hoisted, loop-carried gll source pointers ----
    const int Lr4 = lane >> 4, Lc4 = lane & 15;
    const int Lr3 = lane >> 3, Lc3 = lane & 7;
    const short* ksrc[4]; const short* vsrc[4];
    #pragma unroll
    for (int i = 0; i < 4; ++i) {
        int kr = w * 16 + i * 4 + Lr4;
        ksrc[i] = Kb + (size_t)(b * S + kr) * 512 + g * 128 + (Lc4 ^ (kr & 7)) * 8;
        int vr = w * 32 + i * 8 + Lr3;
        vsrc[i] = Vt + (size_t)(bg * 128 + vr) * 2048 + (Lc3 ^ (vr & 7)) * 8;
    }
    short* kdst = &Ks[(w * 16) * 128];
    short* vdst = &Vs[(w * 32) * 64];

    for (int kv0 = 0; kv0 < S; kv0 += 64) {
        __syncthreads();
        #pragma unroll
        for (int i = 0; i < 4; ++i) {
            GLL16(ksrc[i], kdst + i * 512);
            GLL16(vsrc[i], vdst + i * 512);
        }
        #pragma unroll
        for (int i = 0; i < 4; ++i) { ksrc[i] += 64 * 512; vsrc[i] += 64; }
        __syncthreads();

        // QK^T -> scores [16 q][64 kv]
        f32x4 sc[4] = {};
        #pragma unroll
        for (int kc = 0; kc < 4; ++kc) {
            #pragma unroll
            for (int f = 0; f < 4; ++f) {
                bf16x8 kfr = *(const bf16x8*)(kbase[kc] + f * 2048);
                sc[f] = __builtin_amdgcn_mfma_f32_16x16x32_bf16(qf[kc], kfr, sc[f], 0, 0, 0);
            }
        }

        // tile row maxes (rows q = lg*4+r, cols kv = f*16+lr)
        float mx[4];
        #pragma unroll
        for (int r = 0; r < 4; ++r) {
            float m = fmaxf(fmaxf(sc[0][r], sc[1][r]), fmaxf(sc[2][r], sc[3][r]));
            m = fmaxf(m, __shfl_xor(m, 1));
            m = fmaxf(m, __shfl_xor(m, 2));
            m = fmaxf(m, __shfl_xor(m, 4));
            m = fmaxf(m, __shfl_xor(m, 8));
            mx[r] = m;
        }
        // exact defer: rescale only if some row max actually grew
        bool need = (mx[0] > m_r[0]) | (mx[1] > m_r[1]) | (mx[2] > m_r[2]) | (mx[3] > m_r[3]);
        if (__any(need)) {
            float sf[4];
            #pragma unroll
            for (int r = 0; r < 4; ++r) {
                float mnew = fmaxf(m_r[r], mx[r]);
                sf[r] = exp2f((m_r[r] - mnew) * C);
                m_r[r] = mnew;
                l_r[r] *= sf[r];
            }
            #pragma unroll
            for (int d0 = 0; d0 < 8; ++d0)
                #pragma unroll
                for (int r = 0; r < 4; ++r)
                    ao[d0][r] *= sf[r];
        }
        // exp + row sums + P writes (base + compile-time offsets)
        #pragma unroll
        for (int r = 0; r < 4; ++r) {
            float nmc = -m_r[r] * C;
            float p0 = exp2f(fmaf(sc[0][r], C, nmc));
            float p1 = exp2f(fmaf(sc[1][r], C, nmc));
            float p2 = exp2f(fmaf(sc[2][r], C, nmc));
            float p3 = exp2f(fmaf(sc[3][r], C, nmc));
            float rs = (p0 + p1) + (p2 + p3);
            rs += __shfl_xor(rs, 1);
            rs += __shfl_xor(rs, 2);
            rs += __shfl_xor(rs, 4);
            rs += __shfl_xor(rs, 8);
            l_r[r] += rs;
            pwb[0 * 256 + r * 8] = f2bf(p0);
            pwb[1 * 256 + r * 8] = f2bf(p1);
            pwb[2 * 256 + r * 8] = f2bf(p2);
            pwb[3 * 256 + r * 8] = f2bf(p3);
        }

        // PV: O[16 q][128 d] += P[16][64] @ V^T
        bf16x8 pf0 = *(const bf16x8*)(prb);
        bf16x8 pf1 = *(const bf16x8*)(prb + 512);
        #pragma unroll
        for (int d0 = 0; d0 < 8; ++d0) {
            bf16x8 v0 = *(const bf16x8*)(vbase[0] + d0 * 1024);
            bf16x8 v1 = *(const bf16x8*)(vbase[1] + d0 * 1024);
            ao[d0] = __builtin_amdgcn_mfma_f32_16x16x32_bf16(pf0, v0, ao[d0], 0, 0, 0);
            ao[d0] = __builtin_amdgcn_mfma_f32_16x16x32_bf16(pf1, v1, ao[d0], 0, 0, 0);
        }
    }

    #pragma unroll
    for (int d0 = 0; d0 < 8; ++d0) {
        #pragma unroll
        for (int r = 0; r < 4; ++r) {
            float v = ao[d0][r] / l_r[r];
            int q = q0 + lg * 4 + r;
            Ob[(size_t)(b * S + q) * 2048 + h * 128 + d0 * 16 + lr] = f2bf(v);
        }
    }
}

extern "C" void kernel_launch(void* const* d_in, const int* in_sizes, int n_in,
                              void* d_out, int out_size, void* d_ws, size_t ws_size,
                              hipStream_t stream)
{
    const float* query = (const float*)d_in[0];
    const float* key   = (const float*)d_in[1];
    const float* value = (const float*)d_in[2];
    const float* Wq    = (const float*)d_in[3];
    const float* bq    = (const float*)d_in[4];
    const float* Wk    = (const float*)d_in[5];
    const float* bk    = (const float*)d_in[6];
    const float* Wv    = (const float*)d_in[7];
    const float* bv    = (const float*)d_in[8];
    const float* Wo    = (const float*)d_in[9];
    const float* bo    = (const float*)d_in[10];
    float* out = (float*)d_out;

    const int BS = 4096;
    char* ws = (char*)d_ws;
    dim3 blk(256);

    if (ws_size >= (size_t)100663296) {
        // ---- full path: fused QKV projection ----
        short* Xq  = (short*)(ws + 0);
        short* Xk  = (short*)(ws + 16777216);
        short* Xv  = (short*)(ws + 33554432);
        short* Qb  = (short*)(ws + 50331648);
        short* Kb  = (short*)(ws + 67108864);
        short* Vb  = (short*)(ws + 71303168);
        short* Vtg = (short*)(ws + 75497472);
        short* WqT = (short*)(ws + 79691776);
        short* WkT = (short*)(ws + 88080384);
        short* WvT = (short*)(ws + 90177536);
        short* WoT = (short*)(ws + 92274688);
        short* Ob  = Xq;  // reuse: Xq dead after gemm_qkv

        transW4<<<dim3(32, 32, 4), blk, 0, stream>>>(Wq, Wk, Wv, Wo, WqT, WkT, WvT, WoT);
        cvt3<<<dim3(4096, 3), blk, 0, stream>>>(query, key, value, Xq, Xk, Xv);
        gemm_qkv<<<768, blk, 0, stream>>>(Xq, Xk, Xv, WqT, WkT, WvT, bq, bk, bv, Qb, Kb, Vb);
        transV<<<dim3(32, 2, 8), blk, 0, stream>>>(Vb, Vtg);
        attn_kernel<<<dim3(32, 32), blk, 0, stream>>>(Qb, Kb, Vtg, Ob);
        gemm_std<float><<<512, blk, 0, stream>>>(Ob, WoT, bo, out, 2048, 2048);
    } else {
        // ---- fallback: sequential (ws >= 64 MiB guaranteed by round-2 evidence) ----
        short* Qb  = (short*)(ws + 0);
        short* Kb  = (short*)(ws + 16777216);
        short* Vb  = (short*)(ws + 20971520);
        short* Vtg = (short*)(ws + 25165824);
        short* WqT = (short*)(ws + 29360128);
        short* WkT = (short*)(ws + 37748736);
        short* WvT = (short*)(ws + 39845888);
        short* WoT = (short*)(ws + 41943040);
        short* Xbf = (short*)(ws + 50331648);

        transW4<<<dim3(32, 32, 4), blk, 0, stream>>>(Wq, Wk, Wv, Wo, WqT, WkT, WvT, WoT);
        cvtk<<<2048, blk, 0, stream>>>(query, Xbf, BS * 2048 / 8);
        gemm_std<short><<<512, blk, 0, stream>>>(Xbf, WqT, bq, Qb, 2048, 2048);
        cvtk<<<2048, blk, 0, stream>>>(key, Xbf, BS * 2048 / 8);
        gemm_std<short><<<128, blk, 0, stream>>>(Xbf, WkT, bk, Kb, 512, 2048);
        cvtk<<<2048, blk, 0, stream>>>(value, Xbf, BS * 2048 / 8);
        gemm_std<short><<<128, blk, 0, stream>>>(Xbf, WvT, bv, Vb, 512, 2048);
        transV<<<dim3(32, 2, 8), blk, 0, stream>>>(Vb, Vtg);
        attn_kernel<<<dim3(32, 32), blk, 0, stream>>>(Qb, Kb, Vtg, Xbf);
        gemm_std<float><<<512, blk, 0, stream>>>(Xbf, WoT, bo, out, 2048, 2048);
    }
}

// Round 5
// 266.443 us; speedup vs baseline: 2.8213x; 1.1777x over previous
//
#include <hip/hip_runtime.h>
#include <hip/hip_bf16.h>
#include <type_traits>
#include <stdint.h>

typedef short bf16x8 __attribute__((ext_vector_type(8)));
typedef short short4v __attribute__((ext_vector_type(4)));
typedef float f32x4 __attribute__((ext_vector_type(4)));
typedef float f32x16 __attribute__((ext_vector_type(16)));

#define GLL16(gp, lp) __builtin_amdgcn_global_load_lds( \
    (const __attribute__((address_space(1))) void*)(gp), \
    (__attribute__((address_space(3))) void*)(lp), 16, 0, 0)

__device__ inline short f2bf(float f) {
    union { float f; uint32_t u; } v;
    v.f = f;
    uint32_t r = (v.u + 0x7FFFu + ((v.u >> 16) & 1u)) >> 16;
    return (short)(uint16_t)r;
}

__device__ inline bf16x8 cvt8(const float4& a, const float4& b) {
    bf16x8 o;
    o[0] = f2bf(a.x); o[1] = f2bf(a.y); o[2] = f2bf(a.z); o[3] = f2bf(a.w);
    o[4] = f2bf(b.x); o[5] = f2bf(b.y); o[6] = f2bf(b.z); o[7] = f2bf(b.w);
    return o;
}

// pack 2 f32 -> u32 of 2 bf16 (RNE)
__device__ inline uint32_t cvtpk(float lo, float hi) {
    uint32_t r;
    asm("v_cvt_pk_bf16_f32 %0, %1, %2" : "=v"(r) : "v"(lo), "v"(hi));
    return r;
}

__device__ inline bf16x8 mk8(uint32_t a, uint32_t b, uint32_t c, uint32_t d) {
    union { uint32_t u[4]; bf16x8 v; } t;
    t.u[0] = a; t.u[1] = b; t.u[2] = c; t.u[3] = d;
    return t.v;
}

// Exchange packed P-words between hi/lo half-wave partners (lane ^ 32).
// Input c[0..7] = lane's 8 packed kv-pairs of one 32-kv block:
//   lane(hi) word i: kv pair base = 4*hi + 2*(i&1) + 8*(i>>1)  [i.e. e-pairs]
// Output fA = kv slice [0,16) in mfma-k order (k = hi*8+jj), fB = slice [16,32).
__device__ inline void xchg_pf(const uint32_t c[8], bool hib, bf16x8& fA, bf16x8& fB) {
    uint32_t p0 = (uint32_t)__shfl_xor((int)c[0], 32);
    uint32_t p1 = (uint32_t)__shfl_xor((int)c[1], 32);
    uint32_t p2 = (uint32_t)__shfl_xor((int)c[2], 32);
    uint32_t p3 = (uint32_t)__shfl_xor((int)c[3], 32);
    fA = mk8(hib ? p2 : c[0], hib ? p3 : c[1], hib ? c[2] : p0, hib ? c[3] : p1);
    uint32_t p4 = (uint32_t)__shfl_xor((int)c[4], 32);
    uint32_t p5 = (uint32_t)__shfl_xor((int)c[5], 32);
    uint32_t p6 = (uint32_t)__shfl_xor((int)c[6], 32);
    uint32_t p7 = (uint32_t)__shfl_xor((int)c[7], 32);
    fB = mk8(hib ? p6 : c[4], hib ? p7 : c[5], hib ? c[6] : p4, hib ? c[7] : p5);
}

// ---------------- single f32 -> bf16 convert (fallback) ----------------
__global__ __launch_bounds__(256) void cvtk(const float* __restrict__ in,
                                            short* __restrict__ out, int n8)
{
    int i = blockIdx.x * blockDim.x + threadIdx.x;
    int stride = gridDim.x * blockDim.x;
    for (; i < n8; i += stride) {
        const float4* p = (const float4*)(in + (size_t)i * 8);
        float4 a = p[0], b = p[1];
        *(bf16x8*)(out + (size_t)i * 8) = cvt8(a, b);
    }
}

// ---------------- batched q,k,v f32 -> bf16 convert ----------------
__global__ __launch_bounds__(256) void cvt3(
    const float* __restrict__ q, const float* __restrict__ k, const float* __restrict__ v,
    short* __restrict__ Xq, short* __restrict__ Xk, short* __restrict__ Xv)
{
    const float* in; short* out;
    if (blockIdx.y == 0) { in = q; out = Xq; }
    else if (blockIdx.y == 1) { in = k; out = Xk; }
    else { in = v; out = Xv; }
    size_t i = (size_t)blockIdx.x * 256 + threadIdx.x;
    const float4* p = (const float4*)(in + i * 8);
    float4 a = p[0], b = p[1];
    *(bf16x8*)(out + i * 8) = cvt8(a, b);
}

// ---------------- batched W [K][N] f32 -> WT [N][K] bf16 (4 weights) ----------------
__global__ __launch_bounds__(256) void transW4(
    const float* __restrict__ W0, const float* __restrict__ W1,
    const float* __restrict__ W2, const float* __restrict__ W3,
    short* __restrict__ T0, short* __restrict__ T1,
    short* __restrict__ T2, short* __restrict__ T3)
{
    const int K = 2048;
    const float* W; short* T; int N;
    int z = blockIdx.z;
    if (z == 0)      { W = W0; T = T0; N = 2048; }
    else if (z == 1) { W = W1; T = T1; N = 512; }
    else if (z == 2) { W = W2; T = T2; N = 512; }
    else             { W = W3; T = T3; N = 2048; }
    int n0 = blockIdx.x * 64, k0 = blockIdx.y * 64;
    if (n0 >= N) return;
    __shared__ short Tt[64][65];
    int t = threadIdx.x;
    int kl = t >> 2, nb = (t & 3) * 16;
    const float* wp = W + (size_t)(k0 + kl) * N + n0 + nb;
    #pragma unroll
    for (int j = 0; j < 16; ++j) Tt[nb + j][kl] = f2bf(wp[j]);
    __syncthreads();
    int nl = t >> 2, kb = (t & 3) * 16;
    short* op = T + (size_t)(n0 + nl) * K + k0 + kb;
    #pragma unroll
    for (int j = 0; j < 16; ++j) op[j] = Tt[nl][kb + j];
}

// ---------------- Vb [B*S][512] bf16 -> Vt [8][128][2048] bf16 ----------------
__global__ __launch_bounds__(256) void transV(const short* __restrict__ Vb,
                                              short* __restrict__ Vt)
{
    __shared__ short T[64][65];
    int s0 = blockIdx.x * 64, d0 = blockIdx.y * 64, bg = blockIdx.z;
    int b = bg >> 2, g = bg & 3;
    int t = threadIdx.x;
    int sl = t >> 2, db = (t & 3) * 16;
    const short* vp = Vb + (size_t)(b * 2048 + s0 + sl) * 512 + g * 128 + d0 + db;
    #pragma unroll
    for (int j = 0; j < 16; ++j) T[db + j][sl] = vp[j];
    __syncthreads();
    int dl = t >> 2, sb = (t & 3) * 16;
    short* op = Vt + (size_t)(bg * 128 + d0 + dl) * 2048 + s0 + sb;
    #pragma unroll
    for (int j = 0; j < 16; ++j) op[j] = T[dl][sb + j];
}

// ---------------- bf16 GEMM core: C = A[M,K] @ BT[N,K]^T + bias ----------------
template <typename TC>
__device__ __forceinline__ void gemm_core(
    const short* __restrict__ A, const short* __restrict__ BT,
    const float* __restrict__ bias, TC* __restrict__ C,
    int N, int K, int m0, int n0, short* As, short* Bs)
{
    const int t = threadIdx.x, w = t >> 6, lane = t & 63;
    const int lr = lane & 15, lg = lane >> 4;
    const int wm = (w >> 1) * 64, wn = (w & 1) * 64;
    f32x4 acc[4][4] = {};

    const int lrow = lane >> 3;
    const int lcg = (lane & 7) ^ (lrow & 7);
    const int sw = lr & 7;

    const short* abase[2]; const short* bbase[2];
    #pragma unroll
    for (int kc = 0; kc < 2; ++kc) {
        abase[kc] = &As[(wm + lr) * 64 + (((kc * 4 + lg) ^ sw) * 8)];
        bbase[kc] = &Bs[(wn + lr) * 64 + (((kc * 4 + lg) ^ sw) * 8)];
    }
    const short* asrc = A  + (size_t)(m0 + w * 32 + lrow) * K + lcg * 8;
    const short* bsrc = BT + (size_t)(n0 + w * 32 + lrow) * K + lcg * 8;
    short* adst = &As[(w * 32) * 64];
    short* bdst = &Bs[(w * 32) * 64];

    for (int kk = 0; kk < K; kk += 64) {
        __syncthreads();
        #pragma unroll
        for (int i = 0; i < 4; ++i) {
            GLL16(asrc + (size_t)i * 8 * K, adst + i * 512);
            GLL16(bsrc + (size_t)i * 8 * K, bdst + i * 512);
        }
        asrc += 64; bsrc += 64;
        __syncthreads();
        #pragma unroll
        for (int kc = 0; kc < 2; ++kc) {
            bf16x8 af[4], bfr[4];
            #pragma unroll
            for (int i = 0; i < 4; ++i) af[i] = *(const bf16x8*)(abase[kc] + i * 1024);
            #pragma unroll
            for (int j = 0; j < 4; ++j) bfr[j] = *(const bf16x8*)(bbase[kc] + j * 1024);
            #pragma unroll
            for (int i = 0; i < 4; ++i)
                #pragma unroll
                for (int j = 0; j < 4; ++j)
                    acc[i][j] = __builtin_amdgcn_mfma_f32_16x16x32_bf16(af[i], bfr[j], acc[i][j], 0, 0, 0);
        }
    }

    #pragma unroll
    for (int i = 0; i < 4; ++i) {
        #pragma unroll
        for (int j = 0; j < 4; ++j) {
            #pragma unroll
            for (int r = 0; r < 4; ++r) {
                int row = m0 + wm + i * 16 + lg * 4 + r;
                int col = n0 + wn + j * 16 + lr;
                float v = acc[i][j][r] + bias[col];
                if constexpr (std::is_same<TC, short>::value)
                    C[(size_t)row * N + col] = f2bf(v);
                else
                    C[(size_t)row * N + col] = v;
            }
        }
    }
}

template <typename TC>
__global__ __launch_bounds__(256) void gemm_std(
    const short* __restrict__ A, const short* __restrict__ BT,
    const float* __restrict__ bias, TC* __restrict__ C, int N, int K)
{
    __shared__ short As[128 * 64];
    __shared__ short Bs[128 * 64];
    int bid = blockIdx.x;
    int chunk = gridDim.x >> 3;
    int wg = (bid & 7) * chunk + (bid >> 3);
    int m0 = (wg & 31) * 128, n0 = (wg >> 5) * 128;
    gemm_core<TC>(A, BT, bias, C, N, K, m0, n0, As, Bs);
}

// fused Q/K/V projection (768 blocks, XCD-swizzled)
__global__ __launch_bounds__(256) void gemm_qkv(
    const short* __restrict__ Xq, const short* __restrict__ Xk, const short* __restrict__ Xv,
    const short* __restrict__ WqT, const short* __restrict__ WkT, const short* __restrict__ WvT,
    const float* __restrict__ bq, const float* __restrict__ bk, const float* __restrict__ bv,
    short* __restrict__ Qb, short* __restrict__ Kb, short* __restrict__ Vb)
{
    __shared__ short As[128 * 64];
    __shared__ short Bs[128 * 64];
    int bid = blockIdx.x;
    int wg = (bid & 7) * 96 + (bid >> 3);
    const short* A; const short* BT; const float* bi; short* C; int N; int l;
    if (wg < 512)      { l = wg;       A = Xq; BT = WqT; bi = bq; C = Qb; N = 2048; }
    else if (wg < 640) { l = wg - 512; A = Xk; BT = WkT; bi = bk; C = Kb; N = 512; }
    else               { l = wg - 640; A = Xv; BT = WvT; bi = bv; C = Vb; N = 512; }
    int m0 = (l & 31) * 128, n0 = (l >> 5) * 128;
    gemm_core<short>(A, BT, bi, C, N, 2048, m0, n0, As, Bs);
}

// ---------------- flash attention v5: 32x32 swapped QK^T, shfl exchange, K-style V LDS ----
// Qb [B*S,2048], Kb [B*S,512], Vt [8][128][2048] -> Ob [B*S,2048]   (all bf16)
__global__ __launch_bounds__(256, 2) void attn_kernel(
    const short* __restrict__ Qb, const short* __restrict__ Kb,
    const short* __restrict__ Vt, short* __restrict__ Ob)
{
    const int S = 2048;
    __shared__ short Ks[2 * 64 * 128];   // [buf][kv 64][d 128], slot = c ^ (kv&15)
    __shared__ short Vs[2 * 128 * 64];   // [buf][d 128][kv 64], slot = c ^ (d&7)

    // XCD-chunked swizzle: 64 consecutive wgs (4 heads) per XCD
    int bid = blockIdx.x;
    int wg = (bid & 7) * 64 + (bid >> 3);
    const int qt = wg & 15, bh = wg >> 4;
    const int b = bh >> 4, h = bh & 15, g = h >> 2, bg = b * 4 + g;

    const int t = threadIdx.x, w = t >> 6, lane = t & 63;
    const int l5 = lane & 31, hi = lane >> 5;
    const bool hib = hi != 0;
    const int qg = b * S + qt * 128 + w * 32 + l5;
    const float C = 1.44269504089f;

    // Q fragments (B-operand): qf[dm][j] = Q[qg][h*128 + dm*16 + hi*8 + j]
    const short* qrow = Qb + (size_t)qg * 2048 + h * 128 + hi * 8;
    bf16x8 qf[8];
    #pragma unroll
    for (int dm = 0; dm < 8; ++dm)
        qf[dm] = *(const bf16x8*)(qrow + dm * 16);

    f32x16 o[4] = {};          // O^T[d][q=l5]; d = dblk*32 + (e&3)+8*(e>>2)+4*hi
    float m = -1e30f, l = 0.0f;

    // ---- staging sources (pre-swizzled global addresses) ----
    const int sr4 = lane >> 4, sc4 = lane & 15;   // K: 4 rows x 16 slots per gll
    const int sr8 = lane >> 3, sc8 = lane & 7;    // V: 8 rows x 8 slots per gll
    const short* ksrc[4]; const short* vsrc[4];
    #pragma unroll
    for (int i = 0; i < 4; ++i) {
        int kr = w * 16 + i * 4 + sr4;            // kv row in tile
        ksrc[i] = Kb + (size_t)(b * S + kr) * 512 + g * 128 + ((sc4 ^ (kr & 15)) * 8);
        int d = w * 32 + i * 8 + sr8;             // d row
        vsrc[i] = Vt + (size_t)(bg * 128 + d) * 2048 + ((sc8 ^ (d & 7)) * 8);
    }

    // ---- hoisted LDS read offsets ----
    int kx[8];
    #pragma unroll
    for (int dm = 0; dm < 8; ++dm)
        kx[dm] = (((dm * 2 + hi) ^ (l5 & 15)) * 8);
    int va[4];
    #pragma unroll
    for (int j = 0; j < 4; ++j)
        va[j] = (((2 * j + hi) ^ (l5 & 7)) * 8);

    #define STAGE(BUF, KVI) do { \
        short* kd = Ks + (BUF) * 8192 + (w * 16) * 128; \
        short* vd = Vs + (BUF) * 8192 + (w * 32) * 64; \
        size_t ko = (size_t)(KVI) * 64 * 512; \
        int vo = (KVI) * 64; \
        _Pragma("unroll") \
        for (int i = 0; i < 4; ++i) { \
            GLL16(ksrc[i] + ko, kd + i * 512); \
            GLL16(vsrc[i] + vo, vd + i * 512); \
        } \
    } while (0)

    STAGE(0, 0);
    const int NT = S / 64;
    for (int ti = 0; ti < NT; ++ti) {
        int cur = ti & 1;
        __syncthreads();                       // compiler drains vmcnt(0) before barrier
        if (ti + 1 < NT) STAGE(cur ^ 1, ti + 1);

        // ---- QK^T (swapped): D[kv][q] = K[kv][d] x Q^T[d][q] ----
        const short* KB = Ks + cur * 8192 + l5 * 128;
        f32x16 p0 = {}, p1 = {};
        #pragma unroll
        for (int dm = 0; dm < 8; ++dm) {
            bf16x8 k0 = *(const bf16x8*)(KB + kx[dm]);
            bf16x8 k1 = *(const bf16x8*)(KB + 4096 + kx[dm]);
            p0 = __builtin_amdgcn_mfma_f32_32x32x16_bf16(k0, qf[dm], p0, 0, 0, 0);
            p1 = __builtin_amdgcn_mfma_f32_32x32x16_bf16(k1, qf[dm], p1, 0, 0, 0);
        }

        // ---- online softmax, in-register (q = l5 lane-local) ----
        float mx = -1e30f;
        #pragma unroll
        for (int e = 0; e < 16; ++e) mx = fmaxf(mx, fmaxf(p0[e], p1[e]));
        mx = fmaxf(mx, __shfl_xor(mx, 32));
        if (__any(mx > m)) {                    // exact defer: skip when scale==1
            float mn = fmaxf(m, mx);
            float sf = exp2f((m - mn) * C);
            m = mn; l *= sf;
            #pragma unroll
            for (int dblk = 0; dblk < 4; ++dblk)
                #pragma unroll
                for (int e = 0; e < 16; ++e) o[dblk][e] *= sf;
        }
        float nmc = -m * C;
        #pragma unroll
        for (int e = 0; e < 16; ++e) {
            p0[e] = exp2f(fmaf(p0[e], C, nmc));
            p1[e] = exp2f(fmaf(p1[e], C, nmc));
        }
        float rs = 0.0f;
        #pragma unroll
        for (int e = 0; e < 16; ++e) rs += p0[e] + p1[e];
        rs += __shfl_xor(rs, 32);
        l += rs;

        // ---- P -> bf16 B-fragments (cvt_pk + explicit shfl exchange) ----
        uint32_t c0[8], c1[8];
        #pragma unroll
        for (int i = 0; i < 8; ++i) {
            c0[i] = cvtpk(p0[2 * i], p0[2 * i + 1]);
            c1[i] = cvtpk(p1[2 * i], p1[2 * i + 1]);
        }
        bf16x8 pf[4];
        xchg_pf(c0, hib, pf[0], pf[1]);   // kv [0,16), [16,32)
        xchg_pf(c1, hib, pf[2], pf[3]);   // kv [32,48), [48,64)

        // ---- PV: O^T[d][q] += V^T[d][kv16] x P[kv16][q] ----
        const short* VB = Vs + cur * 8192 + l5 * 64;
        #pragma unroll
        for (int dblk = 0; dblk < 4; ++dblk) {
            const short* vb = VB + dblk * 2048;
            #pragma unroll
            for (int j = 0; j < 4; ++j) {
                bf16x8 vf = *(const bf16x8*)(vb + va[j]);
                o[dblk] = __builtin_amdgcn_mfma_f32_32x32x16_bf16(vf, pf[j], o[dblk], 0, 0, 0);
            }
        }
    }
    #undef STAGE

    // ---- epilogue: O = O^T / l ----
    float inv = 1.0f / l;
    short* op = Ob + (size_t)qg * 2048 + h * 128 + hi * 4;
    #pragma unroll
    for (int dblk = 0; dblk < 4; ++dblk) {
        #pragma unroll
        for (int mm = 0; mm < 4; ++mm) {
            short4v s4;
            #pragma unroll
            for (int e = 0; e < 4; ++e) s4[e] = f2bf(o[dblk][mm * 4 + e] * inv);
            *(short4v*)(op + dblk * 32 + mm * 8) = s4;
        }
    }
}

extern "C" void kernel_launch(void* const* d_in, const int* in_sizes, int n_in,
                              void* d_out, int out_size, void* d_ws, size_t ws_size,
                              hipStream_t stream)
{
    const float* query = (const float*)d_in[0];
    const float* key   = (const float*)d_in[1];
    const float* value = (const float*)d_in[2];
    const float* Wq    = (const float*)d_in[3];
    const float* bq    = (const float*)d_in[4];
    const float* Wk    = (const float*)d_in[5];
    const float* bk    = (const float*)d_in[6];
    const float* Wv    = (const float*)d_in[7];
    const float* bv    = (const float*)d_in[8];
    const float* Wo    = (const float*)d_in[9];
    const float* bo    = (const float*)d_in[10];
    float* out = (float*)d_out;

    const int BS = 4096;
    char* ws = (char*)d_ws;
    dim3 blk(256);

    if (ws_size >= (size_t)100663296) {
        short* Xq  = (short*)(ws + 0);
        short* Xk  = (short*)(ws + 16777216);
        short* Xv  = (short*)(ws + 33554432);
        short* Qb  = (short*)(ws + 50331648);
        short* Kb  = (short*)(ws + 67108864);
        short* Vb  = (short*)(ws + 71303168);
        short* Vtg = (short*)(ws + 75497472);
        short* WqT = (short*)(ws + 79691776);
        short* WkT = (short*)(ws + 88080384);
        short* WvT = (short*)(ws + 90177536);
        short* WoT = (short*)(ws + 92274688);
        short* Ob  = Xq;  // Xq dead after gemm_qkv

        transW4<<<dim3(32, 32, 4), blk, 0, stream>>>(Wq, Wk, Wv, Wo, WqT, WkT, WvT, WoT);
        cvt3<<<dim3(4096, 3), blk, 0, stream>>>(query, key, value, Xq, Xk, Xv);
        gemm_qkv<<<768, blk, 0, stream>>>(Xq, Xk, Xv, WqT, WkT, WvT, bq, bk, bv, Qb, Kb, Vb);
        transV<<<dim3(32, 2, 8), blk, 0, stream>>>(Vb, Vtg);
        attn_kernel<<<512, blk, 0, stream>>>(Qb, Kb, Vtg, Ob);
        gemm_std<float><<<512, blk, 0, stream>>>(Ob, WoT, bo, out, 2048, 2048);
    } else {
        short* Qb  = (short*)(ws + 0);
        short* Kb  = (short*)(ws + 16777216);
        short* Vb  = (short*)(ws + 20971520);
        short* Vtg = (short*)(ws + 25165824);
        short* WqT = (short*)(ws + 29360128);
        short* WkT = (short*)(ws + 37748736);
        short* WvT = (short*)(ws + 39845888);
        short* WoT = (short*)(ws + 41943040);
        short* Xbf = (short*)(ws + 50331648);

        transW4<<<dim3(32, 32, 4), blk, 0, stream>>>(Wq, Wk, Wv, Wo, WqT, WkT, WvT, WoT);
        cvtk<<<2048, blk, 0, stream>>>(query, Xbf, BS * 2048 / 8);
        gemm_std<short><<<512, blk, 0, stream>>>(Xbf, WqT, bq, Qb, 2048, 2048);
        cvtk<<<2048, blk, 0, stream>>>(key, Xbf, BS * 2048 / 8);
        gemm_std<short><<<128, blk, 0, stream>>>(Xbf, WkT, bk, Kb, 512, 2048);
        cvtk<<<2048, blk, 0, stream>>>(value, Xbf, BS * 2048 / 8);
        gemm_std<short><<<128, blk, 0, stream>>>(Xbf, WvT, bv, Vb, 512, 2048);
        transV<<<dim3(32, 2, 8), blk, 0, stream>>>(Vb, Vtg);
        attn_kernel<<<512, blk, 0, stream>>>(Qb, Kb, Vtg, Xbf);
        gemm_std<float><<<512, blk, 0, stream>>>(Xbf, WoT, bo, out, 2048, 2048);
    }
}